// Round 2
// baseline (555.647 us; speedup 1.0000x reference)
//
#include <hip/hip_runtime.h>

typedef __bf16 bf16_t;
typedef bf16_t bf16x8 __attribute__((ext_vector_type(8)));
typedef float f32x4 __attribute__((ext_vector_type(4)));

#define MFMA16(a, b, c) __builtin_amdgcn_mfma_f32_16x16x32_bf16((a), (b), (c), 0, 0, 0)

// ---------------- fill: sigma plane (1.0 / 0.25), mus[0]=0, zs[0]=noise0 ----------------
__global__ void fill_out_kernel(const float* __restrict__ noise0, float* __restrict__ out) {
  const int SLAB = 2048 * 256;   // one (B,Z) slab
  const int SZ = 17 * SLAB;      // one output plane
  int i = (blockIdx.x * blockDim.x + threadIdx.x) * 4;
  if (i >= 19 * SLAB) return;
  float4 v;
  int dst;
  if (i < 17 * SLAB) {                       // sigmas plane (s=2)
    float x = (i < SLAB) ? 1.0f : 0.25f;
    v = make_float4(x, x, x, x);
    dst = 2 * SZ + i;
  } else if (i < 18 * SLAB) {                // mus (s=1), t=0 slab
    v = make_float4(0.f, 0.f, 0.f, 0.f);
    dst = SZ + (i - 17 * SLAB);
  } else {                                   // zs (s=0), t=0 slab = noise0
    v = *(const float4*)(noise0 + (i - 18 * SLAB));
    dst = i - 18 * SLAB;
  }
  *(float4*)(out + dst) = v;
}

// ---------------- f32 -> bf16 plain cast ----------------
__global__ void cast_bf16_kernel(const float* __restrict__ src, bf16_t* __restrict__ dst, int n) {
  int i = (blockIdx.x * blockDim.x + threadIdx.x) * 4;
  if (i >= n) return;
#pragma unroll
  for (int j = 0; j < 4; ++j) dst[i + j] = (bf16_t)src[i + j];
}

// ---------------- pack KxN f32 weight into MFMA B-fragment order ----------------
// dst[((kt*NT + nt)*64 + lane)*8 + j] = src[kt*32 + 8*(lane>>4) + j][nt*16 + (lane&15)]
__global__ void pack_b_kernel(const float* __restrict__ src, bf16_t* __restrict__ dst, int K, int N) {
  int tid = blockIdx.x * blockDim.x + threadIdx.x;   // one per (kt, nt, lane)
  int NT = N >> 4;
  if (tid >= (K >> 5) * NT * 64) return;
  int l = tid & 63;
  int grp = tid >> 6;
  int nt = grp % NT, kt = grp / NT;
  int r = l & 15, g = l >> 4;
  const float* s = src + (size_t)(kt * 32 + 8 * g) * N + nt * 16 + r;
  bf16_t* d = dst + (size_t)tid * 8;
#pragma unroll
  for (int j = 0; j < 8; ++j) d[j] = (bf16_t)s[(size_t)j * N];
}

// ---------------- generic bf16 MFMA GEMM: C = A(MxK, bf16 row-major) @ Bpacked (+bias) ----------------
__global__ __launch_bounds__(256) void gemm_bf16_kernel(
    const bf16_t* __restrict__ A, const bf16_t* __restrict__ Bp,
    const float* __restrict__ bias, float* __restrict__ C,
    int M, int N, int K, int useBias)
{
  int l = threadIdx.x & 63, w = threadIdx.x >> 6;
  int r = l & 15, g = l >> 4;
  int rowbase = blockIdx.x * 64 + w * 16;
  int colbase = blockIdx.y * 64;
  int NT = N >> 4;
  const bf16x8* Bv = (const bf16x8*)Bp;
  f32x4 acc[4] = {};
  for (int kt = 0; kt < (K >> 5); ++kt) {
    bf16x8 af = *(const bf16x8*)(A + (size_t)(rowbase + r) * K + kt * 32 + 8 * g);
#pragma unroll
    for (int nt = 0; nt < 4; ++nt) {
      bf16x8 bf = Bv[(size_t)(kt * NT + (colbase >> 4) + nt) * 64 + l];
      acc[nt] = MFMA16(af, bf, acc[nt]);
    }
  }
#pragma unroll
  for (int nt = 0; nt < 4; ++nt) {
    int col = colbase + nt * 16 + r;
    float bv = useBias ? bias[col] : 0.f;
#pragma unroll
    for (int q = 0; q < 4; ++q) {
      int row = rowbase + 4 * g + q;
      C[(size_t)row * N + col] = acc[nt][q] + bv;
    }
  }
}

// ---------------- tadd[t][n] = sum_k relu((t+1)/16 * Wt[k] + bt[k]) * W0[k][n] ----------------
__global__ void tadd_kernel(const float* __restrict__ W0, const float* __restrict__ Wt,
                            const float* __restrict__ bt, float* __restrict__ tadd) {
  int t = blockIdx.x;
  int n = threadIdx.x;   // 512
  float ts = (t + 1) * 0.0625f;
  float s = 0.f;
#pragma unroll 4
  for (int k = 0; k < 768; ++k) {
    float e = fmaxf(ts * Wt[k] + bt[k], 0.f);
    s = fmaf(e, W0[k * 512 + n], s);
  }
  tadd[t * 512 + n] = s;
}

// ---------------- bo2[n] = bo[n] + sum_k bh[k]*(T3[k][n] + Wo[k][n]) ----------------
__global__ void bo2_kernel(const float* __restrict__ bh, const float* __restrict__ T3f,
                           const float* __restrict__ Wo, const float* __restrict__ bo,
                           float* __restrict__ bo2) {
  int n = threadIdx.x;   // 256
  float s = bo[n];
#pragma unroll 4
  for (int k = 0; k < 512; ++k)
    s = fmaf(bh[k], T3f[k * 256 + n] + Wo[k * 256 + n], s);
  bo2[n] = s;
}

// ---------------- main persistent loop: 128 WGs x 512 threads, 16 rows/WG, all 16 steps ----------------
__global__ __launch_bounds__(512) void diffusion_main_kernel(
    const bf16_t* __restrict__ W0zp,   // [8][32][64][8]  (K=256, N=512)
    const bf16_t* __restrict__ Wfp,    // [16][16][64][8] (K=512, N=256)
    const float* __restrict__ base,    // [2048][512] = r@W0r + b0
    const float* __restrict__ tadd,    // [16][512]
    const float* __restrict__ bo2,     // [256]
    const float* __restrict__ noise0,  // [2048][256]
    const float* __restrict__ noise,   // [16][2048][256]
    float* __restrict__ out)           // [3][17][2048][256]
{
  __shared__ bf16_t zbuf[16 * 256];
  __shared__ bf16_t abuf[16 * 512];
  const int tid = threadIdx.x;
  const int w = tid >> 6, l = tid & 63;
  const int r = l & 15, g = l >> 4;
  const int brow = blockIdx.x << 4;

  // per-lane constants: GEMM1 acc-init (base), GEMM2 acc-init (bo2)
  f32x4 base_reg[4];
#pragma unroll
  for (int nt = 0; nt < 4; ++nt)
#pragma unroll
    for (int q = 0; q < 4; ++q)
      base_reg[nt][q] = base[(size_t)(brow + 4 * g + q) * 512 + w * 64 + nt * 16 + r];
  float bo_reg[2];
#pragma unroll
  for (int nt = 0; nt < 2; ++nt) bo_reg[nt] = bo2[w * 32 + nt * 16 + r];

  // z state in f32 C-layout registers; wave w owns z cols [w*32, w*32+32)
  f32x4 zst[2];
#pragma unroll
  for (int nt = 0; nt < 2; ++nt)
#pragma unroll
    for (int q = 0; q < 4; ++q)
      zst[nt][q] = noise0[(size_t)(brow + 4 * g + q) * 256 + w * 32 + nt * 16 + r];

#pragma unroll
  for (int nt = 0; nt < 2; ++nt)
#pragma unroll
    for (int q = 0; q < 4; ++q) {
      int row = 4 * g + q, col = w * 32 + nt * 16 + r;
      zbuf[(row * 256 + col) ^ ((row & 7) << 3)] = (bf16_t)zst[nt][q];
    }
  __syncthreads();

  const bf16x8* W0v = (const bf16x8*)W0zp;
  const bf16x8* Wfv = (const bf16x8*)Wfp;

#pragma unroll 1
  for (int t = 0; t < 16; ++t) {
    // prefetch eps early (HBM latency hides under GEMMs)
    float ep[2][4];
#pragma unroll
    for (int nt = 0; nt < 2; ++nt)
#pragma unroll
      for (int q = 0; q < 4; ++q)
        ep[nt][q] = noise[((size_t)t * 2048 + brow + 4 * g + q) * 256 + w * 32 + nt * 16 + r];

    // z A-fragments from swizzled LDS (row = lane&15, k = kt*32 + 8*(lane>>4) + j)
    bf16x8 zf[8];
#pragma unroll
    for (int kt = 0; kt < 8; ++kt) {
      int e = (r * 256 + kt * 32 + 8 * g) ^ ((r & 7) << 3);
      zf[kt] = *(const bf16x8*)&zbuf[e];
    }

    // GEMM1: h1 = z @ W0z, acc pre-initialized with base + tadd[t]
    f32x4 acc1[4];
#pragma unroll
    for (int nt = 0; nt < 4; ++nt) {
      float tv = tadd[t * 512 + w * 64 + nt * 16 + r];
#pragma unroll
      for (int q = 0; q < 4; ++q) acc1[nt][q] = base_reg[nt][q] + tv;
    }
#pragma unroll
    for (int kt = 0; kt < 8; ++kt)
#pragma unroll
      for (int nt = 0; nt < 4; ++nt)
        acc1[nt] = MFMA16(zf[kt], W0v[(size_t)(kt * 32 + w * 4 + nt) * 64 + l], acc1[nt]);

    // a = relu(h1) -> abuf (bf16, XOR-swizzled)
#pragma unroll
    for (int nt = 0; nt < 4; ++nt)
#pragma unroll
      for (int q = 0; q < 4; ++q) {
        int row = 4 * g + q, col = w * 64 + nt * 16 + r;
        abuf[(row * 512 + col) ^ ((row & 7) << 3)] = (bf16_t)fmaxf(acc1[nt][q], 0.f);
      }
    __syncthreads();   // B1: abuf complete; zbuf reads of this step done

    // GEMM2: score = a @ Wf + bo2
    f32x4 acc2[2];
#pragma unroll
    for (int nt = 0; nt < 2; ++nt)
#pragma unroll
      for (int q = 0; q < 4; ++q) acc2[nt][q] = bo_reg[nt];
#pragma unroll
    for (int kt = 0; kt < 16; ++kt) {
      int e = (r * 512 + kt * 32 + 8 * g) ^ ((r & 7) << 3);
      bf16x8 af = *(const bf16x8*)&abuf[e];
#pragma unroll
      for (int nt = 0; nt < 2; ++nt)
        acc2[nt] = MFMA16(af, Wfv[(size_t)(kt * 16 + w * 2 + nt) * 64 + l], acc2[nt]);
    }

    // z update + write zs[t+1], mus[t+1]
#pragma unroll
    for (int nt = 0; nt < 2; ++nt)
#pragma unroll
      for (int q = 0; q < 4; ++q) {
        int row = 4 * g + q, col = w * 32 + nt * 16 + r;
        int grow = brow + row;
        float mu = fmaf(acc2[nt][q], 0.0625f, zst[nt][q]);   // z + score*dt
        float zn = fmaf(ep[nt][q], 0.25f, mu);               // + sqrt(dt)*eps
        zst[nt][q] = zn;
        out[((size_t)(t + 1) * 2048 + grow) * 256 + col] = zn;            // zs plane
        out[((size_t)(17 + t + 1) * 2048 + grow) * 256 + col] = mu;       // mus plane
        zbuf[(row * 256 + col) ^ ((row & 7) << 3)] = (bf16_t)zn;
      }
    __syncthreads();   // B2: zbuf(t+1) complete before next step's reads
  }
}

extern "C" void kernel_launch(void* const* d_in, const int* in_sizes, int n_in,
                              void* d_out, int out_size, void* d_ws, size_t ws_size,
                              hipStream_t stream) {
  const float* r   = (const float*)d_in[0];
  const float* n0  = (const float*)d_in[1];
  const float* nz  = (const float*)d_in[2];
  const float* W0  = (const float*)d_in[3];
  const float* b0  = (const float*)d_in[4];
  const float* Wh  = (const float*)d_in[5];
  const float* bh  = (const float*)d_in[6];
  const float* Wo  = (const float*)d_in[7];
  const float* bo  = (const float*)d_in[8];
  const float* Wt  = (const float*)d_in[9];
  const float* bt  = (const float*)d_in[10];
  float* out = (float*)d_out;

  char* ws = (char*)d_ws;
  size_t off = 0;
  auto alloc = [&](size_t bytes) -> char* {
    char* p = ws + off;
    off += (bytes + 255) & ~(size_t)255;
    return p;
  };
  bf16_t* r_bf  = (bf16_t*)alloc((size_t)2048 * 512 * 2);
  bf16_t* Wh_bf = (bf16_t*)alloc((size_t)512 * 512 * 2);
  bf16_t* W0zp  = (bf16_t*)alloc((size_t)256 * 512 * 2);
  bf16_t* W0rp  = (bf16_t*)alloc((size_t)512 * 512 * 2);
  bf16_t* Wop   = (bf16_t*)alloc((size_t)512 * 256 * 2);
  float*  T3f   = (float*) alloc((size_t)512 * 256 * 4);
  bf16_t* T3p   = (bf16_t*)alloc((size_t)512 * 256 * 2);
  float*  Wff   = (float*) alloc((size_t)512 * 256 * 4);
  bf16_t* Wfp   = (bf16_t*)alloc((size_t)512 * 256 * 2);
  float*  baseb = (float*) alloc((size_t)2048 * 512 * 4);
  float*  taddb = (float*) alloc((size_t)16 * 512 * 4);
  float*  bo2b  = (float*) alloc((size_t)256 * 4);
  if (off > ws_size) return;   // workspace too small — bail (will fail validation loudly)

  // constant output regions (sigmas, mus[0], zs[0])
  fill_out_kernel<<<9728, 256, 0, stream>>>(n0, out);

  // casts
  cast_bf16_kernel<<<1024, 256, 0, stream>>>(r, r_bf, 2048 * 512);
  cast_bf16_kernel<<<256, 256, 0, stream>>>(Wh, Wh_bf, 512 * 512);

  // weight packs (MFMA B-fragment order)
  pack_b_kernel<<<64, 256, 0, stream>>>(W0, W0zp, 256, 512);              // W0[0:256]
  pack_b_kernel<<<128, 256, 0, stream>>>(W0 + 256 * 512, W0rp, 512, 512); // W0[256:768]
  pack_b_kernel<<<64, 256, 0, stream>>>(Wo, Wop, 512, 256);

  // Wf = Wh @ (Wh @ Wo), bo2 = bh@T3 + bh@Wo + bo
  gemm_bf16_kernel<<<dim3(8, 4), 256, 0, stream>>>(Wh_bf, Wop, nullptr, T3f, 512, 256, 512, 0);
  pack_b_kernel<<<64, 256, 0, stream>>>(T3f, T3p, 512, 256);
  gemm_bf16_kernel<<<dim3(8, 4), 256, 0, stream>>>(Wh_bf, T3p, nullptr, Wff, 512, 256, 512, 0);
  pack_b_kernel<<<64, 256, 0, stream>>>(Wff, Wfp, 512, 256);

  // base = r @ W0r + b0
  gemm_bf16_kernel<<<dim3(32, 8), 256, 0, stream>>>(r_bf, W0rp, b0, baseb, 2048, 512, 512, 1);

  tadd_kernel<<<16, 512, 0, stream>>>(W0, Wt, bt, taddb);
  bo2_kernel<<<1, 256, 0, stream>>>(bh, T3f, Wo, bo, bo2b);

  // the whole 16-step diffusion loop in one persistent kernel
  diffusion_main_kernel<<<128, 512, 0, stream>>>(W0zp, Wfp, baseb, taddb, bo2b, n0, nz, out);
}